// Round 1
// baseline (4807.386 us; speedup 1.0000x reference)
//
#include <hip/hip_runtime.h>
#include <math.h>

// DEC_LO exactly as in the reference; DEC_HI[k] = (-1)^(k+1) * DEC_LO[11-k]
__constant__ float F_LO[12] = {
    -0.00107730108499558f,  0.004777257511010651f, 0.0005538422009938016f,
    -0.031582039318031156f, 0.02752286553001629f,  0.09750160558707936f,
    -0.12976686756709563f,  -0.22626469396516913f, 0.3152503517092432f,
    0.7511339080215775f,    0.4946238903983854f,   0.11154074335008017f };
__constant__ float F_HI[12] = {
    -0.11154074335008017f,  0.4946238903983854f,   -0.7511339080215775f,
    0.3152503517092432f,    0.22626469396516913f,  -0.12976686756709563f,
    -0.09750160558707936f,  0.02752286553001629f,  0.031582039318031156f,
    0.0005538422009938016f, -0.004777257511010651f, -0.00107730108499558f };

__device__ __forceinline__ int reflect_idx(int i, int N) {
    while (i < 0 || i >= N) {
        if (i < 0) i = -1 - i;
        else       i = 2 * N - 1 - i;
    }
    return i;
}

__device__ __forceinline__ float gelu_f(float x) {
    return 0.5f * x * (1.0f + erff(x * 0.7071067811865475f));
}

#define GSL(total) for (long idx = (long)blockIdx.x * blockDim.x + threadIdx.x; \
                        idx < (total); idx += (long)gridDim.x * blockDim.x)

// ---------------- diagnostic fill (guard path) ------------------------------------
__global__ void fill_kernel(float* __restrict__ out, long n, float v)
{
    GSL(n) out[idx] = v;
}

// ---------------- fc0: x(8,255,255,4)@(4,48)+b -> A(8,48,256,256), zero pad to 256 --
__global__ void fc0_kernel(const float* __restrict__ x, const float* __restrict__ w,
                           const float* __restrict__ b, float* __restrict__ out)
{
    GSL(8L * 48 * 65536) {
        int xx = idx & 255;
        int y  = ((int)(idx >> 8)) & 255;
        int bc = (int)(idx >> 16);          // b*48 + c
        int c  = bc % 48;
        float v = 0.f;
        if (y < 255 && xx < 255) {
            int bb = bc / 48;
            const float* xp = x + (((size_t)(bb * 255 + y) * 255 + xx) << 2);
            v = b[c] + xp[0] * w[c] + xp[1] * w[48 + c] + xp[2] * w[96 + c] + xp[3] * w[144 + c];
        }
        out[idx] = v;
    }
}

// ---------------- analysis along x: in (R,NY,NX) -> lo,hi (R,NY,OX) ----------------
__global__ void dwt_x_kernel(const float* __restrict__ in, float* __restrict__ lo,
                             float* __restrict__ hi, int R, int NY, int NX, int OX)
{
    GSL((long)R * NY * OX) {
        int u = (int)(idx % OX);
        long t = idx / OX;
        int y = (int)(t % NY);
        int r = (int)(t / NY);
        const float* row = in + ((size_t)r * NY + y) * NX;
        float la = 0.f, ha = 0.f;
        #pragma unroll
        for (int k = 0; k < 12; ++k) {
            int m = reflect_idx(2 * u + k - 10, NX);
            float v = row[m];
            la += v * F_LO[11 - k];
            ha += v * F_HI[11 - k];
        }
        size_t o = ((size_t)r * NY + y) * OX + u;
        lo[o] = la;
        hi[o] = ha;
    }
}

// ---------------- analysis along y, TWO independent problems in one launch ---------
// Problem A: inA -> loA,hiA; Problem B: inB -> loB,hiB. Same geometry.
__global__ void dwt_y_pair_kernel(const float* __restrict__ inA, float* __restrict__ loA,
                                  float* __restrict__ hiA,
                                  const float* __restrict__ inB, float* __restrict__ loB,
                                  float* __restrict__ hiB,
                                  int R, int NY, int NX, int OY)
{
    long base = (long)R * OY * NX;
    GSL(2 * base) {
        const float* in; float* lo; float* hi;
        long id2;
        if (idx < base) { in = inA; lo = loA; hi = hiA; id2 = idx; }
        else            { in = inB; lo = loB; hi = hiB; id2 = idx - base; }
        int x = (int)(id2 % NX);
        long t = id2 / NX;
        int u = (int)(t % OY);
        int r = (int)(t / OY);
        const float* sheet = in + (size_t)r * NY * NX;
        float la = 0.f, ha = 0.f;
        #pragma unroll
        for (int k = 0; k < 12; ++k) {
            int m = reflect_idx(2 * u + k - 10, NY);
            float v = sheet[(size_t)m * NX + x];
            la += v * F_LO[11 - k];
            ha += v * F_HI[11 - k];
        }
        size_t o = ((size_t)r * OY + u) * NX + x;
        lo[o] = la;
        hi[o] = ha;
    }
}

// ---------------- synthesis along y, TWO independent problems in one launch --------
// out[u] = sum_k xp[u+k]*DEC[k] with xp = zero-upsampled (odd j) coeffs; per-problem
// strides allow cropped (134->133) views.
__global__ void idwt_y_pair_kernel(
        const float* __restrict__ loA, const float* __restrict__ hiA, float* __restrict__ outA,
        int rslA, int sslA, int rshA, int sshA,
        const float* __restrict__ loB, const float* __restrict__ hiB, float* __restrict__ outB,
        int rslB, int sslB, int rshB, int sshB,
        int R, int n, int NX)
{
    int OY = 2 * n - 10;
    long base = (long)R * OY * NX;
    GSL(2 * base) {
        const float *lo, *hi; float* out; int rsl, ssl, rsh, ssh; long id2;
        if (idx < base) { lo=loA; hi=hiA; out=outA; rsl=rslA; ssl=sslA; rsh=rshA; ssh=sshA; id2=idx; }
        else            { lo=loB; hi=hiB; out=outB; rsl=rslB; ssl=sslB; rsh=rshB; ssh=sshB; id2=idx-base; }
        int x = (int)(id2 % NX);
        long t = id2 / NX;
        int u = (int)(t % OY);
        int r = (int)(t / OY);
        const float* lop = lo + (size_t)r * ssl + x;
        const float* hp  = hi + (size_t)r * ssh + x;
        float acc = 0.f;
        #pragma unroll
        for (int k = 0; k < 12; ++k) {
            int j = u + k;
            if (j & 1) {
                int i = (j - 1) >> 1;
                if (i < n)
                    acc += lop[(size_t)i * rsl] * F_LO[k] + hp[(size_t)i * rsh] * F_HI[k];
            }
        }
        out[((size_t)r * OY + u) * NX + x] = acc;
    }
}

// ---------------- synthesis along x (tight layouts) --------------------------------
__global__ void idwt_x_kernel(const float* __restrict__ lo, const float* __restrict__ hi,
                              float* __restrict__ out, int R, int NY, int n)
{
    int OX = 2 * n - 10;
    GSL((long)R * NY * OX) {
        int u = (int)(idx % OX);
        long t = idx / OX;
        int y = (int)(t % NY);
        int r = (int)(t / NY);
        const float* lop = lo + ((size_t)r * NY + y) * n;
        const float* hp  = hi + ((size_t)r * NY + y) * n;
        float acc = 0.f;
        #pragma unroll
        for (int k = 0; k < 12; ++k) {
            int j = u + k;
            if (j & 1) {
                int i = (j - 1) >> 1;
                if (i < n)
                    acc += lop[i] * F_LO[k] + hp[i] * F_HI[k];
            }
        }
        out[((size_t)r * NY + y) * OX + u] = acc;
    }
}

// ---------------- all four coarsest mixes in ONE launch ----------------------------
// q=0: (L3, w+0)   -> L3m ; q=1..3: (Y2+(q-1)D3, w+q*WKS) -> Y2m+(q-1)D3
__global__ void mix4_kernel(const float* __restrict__ L3, const float* __restrict__ Y2,
                            const float* __restrict__ wc_l, float* __restrict__ L3m,
                            float* __restrict__ Y2m, long D3, int NB)
{
    const long PER = 48L * 1681;
    const size_t WKS = 48 * 48 * (size_t)1681;
    GSL(4 * PER) {
        int q = (int)(idx / PER);
        long r = idx % PER;
        const float* in = (q == 0) ? L3 : Y2 + (size_t)(q - 1) * D3;
        const float* wk = wc_l + (size_t)q * WKS;
        float* out      = (q == 0) ? L3m : Y2m + (size_t)(q - 1) * D3;
        int p = (int)(r % 1681);
        int o = (int)(r / 1681);
        float acc[8] = {0.f,0.f,0.f,0.f,0.f,0.f,0.f,0.f};
        for (int i = 0; i < 48; ++i) {
            float w = wk[(size_t)(i * 48 + o) * 1681 + p];
            for (int b = 0; b < NB; ++b)
                acc[b] += in[(size_t)(b * 48 + i) * 1681 + p] * w;
        }
        for (int b = 0; b < NB; ++b)
            out[(size_t)(b * 48 + o) * 1681 + p] = acc[b];
    }
}

// ---------------- fused: IDWT-L1 row synthesis + h = act(h1 + cw@h + cb), in place -
// Grid = NB*256*4 blocks. Block = (local batch b, row y, x-tile of 64 px). The block
// stages all 48 channels of its 64 pixels into LDS (coalesced), then 256 threads
// compute 48ch x 64px items (12 per thread). Pixel ownership is exclusive per block,
// so the in-place update of h stays race-free.
__global__ __launch_bounds__(256) void idwt_x_combine_kernel(
        const float* __restrict__ w1a, const float* __restrict__ w1b,
        float* __restrict__ h, const float* __restrict__ cw,
        const float* __restrict__ cb, int do_gelu)
{
    __shared__ float s_h[48 * 64];
    __shared__ float s_w[2304];
    __shared__ float s_b[48];
    int tid = threadIdx.x;
    int bi = blockIdx.x;
    int xt = bi & 3;
    int y  = (bi >> 2) & 255;
    int b  = bi >> 10;
    int x0 = xt << 6;
    for (int j = tid; j < 2304; j += 256) s_w[j] = cw[j];
    if (tid < 48) s_b[tid] = cb[tid];
    for (int j = tid; j < 48 * 64; j += 256) {
        int i = j >> 6, xx = j & 63;
        s_h[j] = h[((size_t)(b * 48 + i) * 256 + y) * 256 + x0 + xx];
    }
    __syncthreads();
    #pragma unroll
    for (int k = 0; k < 12; ++k) {
        int m = (k << 8) + tid;          // per wave: same c, xx = lane (conflict-free)
        int c  = m >> 6;
        int xx = m & 63;
        int x  = x0 + xx;
        const float* lop = w1a + ((size_t)(b * 48 + c) * 256 + y) * 133;
        const float* hp  = w1b + ((size_t)(b * 48 + c) * 256 + y) * 133;
        float h1 = 0.f;
        #pragma unroll
        for (int k2 = 0; k2 < 12; ++k2) {
            int j = x + k2;
            if (j & 1) {
                int i = (j - 1) >> 1;
                if (i < 133)
                    h1 += lop[i] * F_LO[k2] + hp[i] * F_HI[k2];
            }
        }
        float h2 = s_b[c];
        const float* wr = s_w + c * 48;
        const float* vr = s_h + xx;
        #pragma unroll
        for (int i = 0; i < 48; ++i) h2 += wr[i] * vr[i << 6];
        float r = h1 + h2;
        h[((size_t)(b * 48 + c) * 256 + y) * 256 + x] = do_gelu ? gelu_f(r) : r;
    }
}

// ---------------- head: crop 255x255, gelu(h@fc1+b1)@fc2+b2 ------------------------
__global__ __launch_bounds__(256) void head_kernel(const float* __restrict__ h,
        const float* __restrict__ w1, const float* __restrict__ b1,
        const float* __restrict__ w2, const float* __restrict__ b2,
        float* __restrict__ out)
{
    __shared__ float s_w1[3072];
    __shared__ float s_b1[64];
    __shared__ float s_w2[64];
    int tid = threadIdx.x;
    for (int j = tid; j < 3072; j += 256) s_w1[j] = w1[j];
    if (tid < 64) { s_b1[tid] = b1[tid]; s_w2[tid] = w2[tid]; }
    __syncthreads();
    int b = blockIdx.x / 255;
    int y = blockIdx.x % 255;
    if (tid >= 255) return;
    float v[48];
    #pragma unroll
    for (int c = 0; c < 48; ++c)
        v[c] = h[((size_t)(b * 48 + c) * 256 + y) * 256 + tid];
    float acc = b2[0];
    for (int hh = 0; hh < 64; ++hh) {
        float s = s_b1[hh];
        #pragma unroll
        for (int i = 0; i < 48; ++i) s += v[i] * s_w1[i * 64 + hh];
        acc += gelu_f(s) * s_w2[hh];
    }
    out[(size_t)(b * 255 + y) * 255 + tid] = acc;
}

extern "C" void kernel_launch(void* const* d_in, const int* in_sizes, int n_in,
                              void* d_out, int out_size, void* d_ws, size_t ws_size,
                              hipStream_t stream)
{
    const float* x    = (const float*)d_in[0];
    const float* fc0w = (const float*)d_in[1];
    const float* fc0b = (const float*)d_in[2];
    const float* wc[4] = { (const float*)d_in[3], (const float*)d_in[4],
                           (const float*)d_in[5], (const float*)d_in[6] };
    const float* cw   = (const float*)d_in[7];
    const float* cb   = (const float*)d_in[8];
    const float* fc1w = (const float*)d_in[9];
    const float* fc1b = (const float*)d_in[10];
    const float* fc2w = (const float*)d_in[11];
    const float* fc2b = (const float*)d_in[12];
    float* out = (float*)d_out;
    (void)in_sizes; (void)n_in;

    // ---- batch-chunked workspace plan (adaptive; cb_n=1 needs 127.4 MB) ----------
    const size_t A_F     = 25165824;  // (8,48,256,256)
    const size_t PER_SHT = 139119;    // 68096 (W1/mid) + 53067 (Y0) + 17956 (L1)
    int cb_n = 0;
    for (int c = 8; c >= 1; c >>= 1) {
        if ((A_F + (size_t)c * 48 * PER_SHT) * 4ull <= ws_size) { cb_n = c; break; }
    }
    if (cb_n == 0) {
        fill_kernel<<<dim3(2033), 256, 0, stream>>>(out, (long)out_size,
                                                    (float)(ws_size >> 20));
        return;
    }
    const int S = cb_n * 48;
    float* ws = (float*)d_ws;
    float* A    = ws;
    float* CH   = A + A_F;
    float* W1a  = CH;                           // (S,256,133)
    float* W1b  = CH + (size_t)S * 34048;
    float* Y0   = CH + (size_t)S * 68096;       // 3 x (S,133,133)
    float* L1c  = Y0 + (size_t)S * 53067;       // (S,134,134)
    float* W2a  = CH;                           // mid-phase aliases W1 region
    float* W2b  = W2a + (size_t)S * 9648;
    float* Y1   = W2b + (size_t)S * 9648;
    float* L2   = Y1  + (size_t)S * 3 * 5184;
    float* W3a  = L2  + (size_t)S * 5184;
    float* W3b  = W3a + (size_t)S * 2952;
    float* Y2   = W3b + (size_t)S * 2952;
    float* Y2m  = Y2  + (size_t)S * 3 * 1681;
    float* L3   = Y2m + (size_t)S * 3 * 1681;
    float* L3m  = L3  + (size_t)S * 1681;

    const size_t D1 = (size_t)S * 17689, D2 = (size_t)S * 5184, D3 = (size_t)S * 1681;
    auto g = [](long n) { return dim3((unsigned)((n + 255) / 256)); };

    fc0_kernel<<<g(25165824L), 256, 0, stream>>>(x, fc0w, fc0b, A);

    for (int layer = 0; layer < 4; ++layer) {
        const float* w = wc[layer];
        for (int b0 = 0; b0 < 8; b0 += cb_n) {
            float* Ac = A + (size_t)b0 * 48 * 65536;
            // ---- DWT level 1: 256 -> 133
            dwt_x_kernel<<<g((long)S*256*133), 256, 0, stream>>>(Ac, W1a, W1b, S, 256, 256, 133);
            dwt_y_pair_kernel<<<g(2L*S*133*133), 256, 0, stream>>>(
                    W1a, L1c, Y0 + 0*D1, W1b, Y0 + 1*D1, Y0 + 2*D1, S, 256, 133, 133);
            // ---- DWT level 2: 133 -> 72
            dwt_x_kernel<<<g((long)S*133*72), 256, 0, stream>>>(L1c, W2a, W2b, S, 133, 133, 72);
            dwt_y_pair_kernel<<<g(2L*S*72*72), 256, 0, stream>>>(
                    W2a, L2, Y1 + 0*D2, W2b, Y1 + 1*D2, Y1 + 2*D2, S, 133, 72, 72);
            // ---- DWT level 3: 72 -> 41
            dwt_x_kernel<<<g((long)S*72*41), 256, 0, stream>>>(L2, W3a, W3b, S, 72, 72, 41);
            dwt_y_pair_kernel<<<g(2L*S*41*41), 256, 0, stream>>>(
                    W3a, L3, Y2 + 0*D3, W3b, Y2 + 1*D3, Y2 + 2*D3, S, 72, 41, 41);
            // ---- coarsest-level channel mixes, one launch
            mix4_kernel<<<g(4L*48*1681), 256, 0, stream>>>(L3, Y2, w, L3m, Y2m, (long)D3, cb_n);
            // ---- IDWT level 3: 41 -> 72
            idwt_y_pair_kernel<<<g(2L*S*72*41), 256, 0, stream>>>(
                    L3m, Y2m + 0*D3, W3a, 41, 1681, 41, 1681,
                    Y2m + 1*D3, Y2m + 2*D3, W3b, 41, 1681, 41, 1681, S, 41, 41);
            idwt_x_kernel<<<g((long)S*72*72), 256, 0, stream>>>(W3a, W3b, L2, S, 72, 41);
            // ---- IDWT level 2: 72 -> 134
            idwt_y_pair_kernel<<<g(2L*S*134*72), 256, 0, stream>>>(
                    L2, Y1 + 0*D2, W2a, 72, 5184, 72, 5184,
                    Y1 + 1*D2, Y1 + 2*D2, W2b, 72, 5184, 72, 5184, S, 72, 72);
            idwt_x_kernel<<<g((long)S*134*134), 256, 0, stream>>>(W2a, W2b, L1c, S, 134, 72);
            // ---- IDWT level 1: ll (S,134,134) cropped to 133x133 via strides
            idwt_y_pair_kernel<<<g(2L*S*256*133), 256, 0, stream>>>(
                    L1c, Y0 + 0*D1, W1a, 134, 17956, 133, 17689,
                    Y0 + 1*D1, Y0 + 2*D1, W1b, 133, 17689, 133, 17689, S, 133, 133);
            // ---- fused IDWT-L1 row synthesis + combine + activation, in place on Ac
            idwt_x_combine_kernel<<<cb_n * 1024, 256, 0, stream>>>(W1a, W1b, Ac,
                    cw + layer * 2304, cb + layer * 48, layer < 3 ? 1 : 0);
        }
    }

    head_kernel<<<8 * 255, 256, 0, stream>>>(A, fc1w, fc1b, fc2w, fc2b, out);
}

// Round 2
// 3550.265 us; speedup vs baseline: 1.3541x; 1.3541x over previous
//
#include <hip/hip_runtime.h>
#include <math.h>

// DEC_LO exactly as in the reference; DEC_HI[k] = (-1)^(k+1) * DEC_LO[11-k]
__constant__ float F_LO[12] = {
    -0.00107730108499558f,  0.004777257511010651f, 0.0005538422009938016f,
    -0.031582039318031156f, 0.02752286553001629f,  0.09750160558707936f,
    -0.12976686756709563f,  -0.22626469396516913f, 0.3152503517092432f,
    0.7511339080215775f,    0.4946238903983854f,   0.11154074335008017f };
__constant__ float F_HI[12] = {
    -0.11154074335008017f,  0.4946238903983854f,   -0.7511339080215775f,
    0.3152503517092432f,    0.22626469396516913f,  -0.12976686756709563f,
    -0.09750160558707936f,  0.02752286553001629f,  0.031582039318031156f,
    0.0005538422009938016f, -0.004777257511010651f, -0.00107730108499558f };

__device__ __forceinline__ int reflect_idx(int i, int N) {
    while (i < 0 || i >= N) {
        if (i < 0) i = -1 - i;
        else       i = 2 * N - 1 - i;
    }
    return i;
}

__device__ __forceinline__ float gelu_f(float x) {
    return 0.5f * x * (1.0f + erff(x * 0.7071067811865475f));
}

#define GSL(total) for (long idx = (long)blockIdx.x * blockDim.x + threadIdx.x; \
                        idx < (total); idx += (long)gridDim.x * blockDim.x)

// ---------------- diagnostic fill (guard path) ------------------------------------
__global__ void fill_kernel(float* __restrict__ out, long n, float v)
{
    GSL(n) out[idx] = v;
}

// ---------------- fc0: x(8,255,255,4)@(4,48)+b -> A(8,48,256,256), zero pad to 256 --
__global__ void fc0_kernel(const float* __restrict__ x, const float* __restrict__ w,
                           const float* __restrict__ b, float* __restrict__ out)
{
    GSL(8L * 48 * 65536) {
        int xx = idx & 255;
        int y  = ((int)(idx >> 8)) & 255;
        int bc = (int)(idx >> 16);          // b*48 + c
        int c  = bc % 48;
        float v = 0.f;
        if (y < 255 && xx < 255) {
            int bb = bc / 48;
            const float* xp = x + (((size_t)(bb * 255 + y) * 255 + xx) << 2);
            v = b[c] + xp[0] * w[c] + xp[1] * w[48 + c] + xp[2] * w[96 + c] + xp[3] * w[144 + c];
        }
        out[idx] = v;
    }
}

// ---------------- analysis along x: in (R,NY,NX) -> lo,hi (R,NY,OX) ----------------
// Interior outputs (u in [5, (NX-2)/2]) take a branch-free 12-contiguous-tap path;
// only edge outputs run the reflect loop.
__global__ void dwt_x_kernel(const float* __restrict__ in, float* __restrict__ lo,
                             float* __restrict__ hi, int R, int NY, int NX, int OX)
{
    GSL((long)R * NY * OX) {
        int u = (int)(idx % OX);
        long t = idx / OX;
        int y = (int)(t % NY);
        int r = (int)(t / NY);
        const float* row = in + ((size_t)r * NY + y) * NX;
        float la = 0.f, ha = 0.f;
        int base = 2 * u - 10;
        if (base >= 0 && 2 * u + 1 < NX) {
            const float* p = row + base;
            #pragma unroll
            for (int k = 0; k < 12; ++k) {
                float v = p[k];
                la += v * F_LO[11 - k];
                ha += v * F_HI[11 - k];
            }
        } else {
            #pragma unroll
            for (int k = 0; k < 12; ++k) {
                int m = reflect_idx(base + k, NX);
                float v = row[m];
                la += v * F_LO[11 - k];
                ha += v * F_HI[11 - k];
            }
        }
        size_t o = ((size_t)r * NY + y) * OX + u;
        lo[o] = la;
        hi[o] = ha;
    }
}

// ---------------- analysis along y, TWO independent problems in one launch ---------
// Problem A: inA -> loA,hiA; Problem B: inB -> loB,hiB. Same geometry.
__global__ void dwt_y_pair_kernel(const float* __restrict__ inA, float* __restrict__ loA,
                                  float* __restrict__ hiA,
                                  const float* __restrict__ inB, float* __restrict__ loB,
                                  float* __restrict__ hiB,
                                  int R, int NY, int NX, int OY)
{
    long base = (long)R * OY * NX;
    GSL(2 * base) {
        const float* in; float* lo; float* hi;
        long id2;
        if (idx < base) { in = inA; lo = loA; hi = hiA; id2 = idx; }
        else            { in = inB; lo = loB; hi = hiB; id2 = idx - base; }
        int x = (int)(id2 % NX);
        long t = id2 / NX;
        int u = (int)(t % OY);
        int r = (int)(t / OY);
        const float* sheet = in + (size_t)r * NY * NX;
        float la = 0.f, ha = 0.f;
        int mb = 2 * u - 10;
        if (mb >= 0 && 2 * u + 1 < NY) {
            const float* p = sheet + (size_t)mb * NX + x;
            #pragma unroll
            for (int k = 0; k < 12; ++k) {
                float v = p[(size_t)k * NX];
                la += v * F_LO[11 - k];
                ha += v * F_HI[11 - k];
            }
        } else {
            #pragma unroll
            for (int k = 0; k < 12; ++k) {
                int m = reflect_idx(mb + k, NY);
                float v = sheet[(size_t)m * NX + x];
                la += v * F_LO[11 - k];
                ha += v * F_HI[11 - k];
            }
        }
        size_t o = ((size_t)r * OY + u) * NX + x;
        lo[o] = la;
        hi[o] = ha;
    }
}

// ---------------- synthesis along y, TWO independent problems in one launch --------
// Branch-free parity form: out[u] = sum_{t=0..5} lo[u/2+t]*F_LO[2t+1-(u&1)]
//                                 + hi[u/2+t]*F_HI[2t+1-(u&1)]
// (the old `i<n` guard is provably always true for OY = 2n-10). Per-problem strides
// allow cropped (134->133) views.
__global__ void idwt_y_pair_kernel(
        const float* __restrict__ loA, const float* __restrict__ hiA, float* __restrict__ outA,
        int rslA, int sslA, int rshA, int sshA,
        const float* __restrict__ loB, const float* __restrict__ hiB, float* __restrict__ outB,
        int rslB, int sslB, int rshB, int sshB,
        int R, int n, int NX)
{
    int OY = 2 * n - 10;
    long base = (long)R * OY * NX;
    GSL(2 * base) {
        const float *lo, *hi; float* out; int rsl, ssl, rsh, ssh; long id2;
        if (idx < base) { lo=loA; hi=hiA; out=outA; rsl=rslA; ssl=sslA; rsh=rshA; ssh=sshA; id2=idx; }
        else            { lo=loB; hi=hiB; out=outB; rsl=rslB; ssl=sslB; rsh=rshB; ssh=sshB; id2=idx-base; }
        int x = (int)(id2 % NX);
        long t = id2 / NX;
        int u = (int)(t % OY);
        int r = (int)(t / OY);
        int par = u & 1;                  // 0 -> coeffs F[1,3,..11]; 1 -> F[0,2,..10]
        int i0  = u >> 1;
        float cl[6], ch[6];
        #pragma unroll
        for (int tt = 0; tt < 6; ++tt) {
            cl[tt] = F_LO[2 * tt + 1 - par];
            ch[tt] = F_HI[2 * tt + 1 - par];
        }
        const float* lop = lo + (size_t)r * ssl + (size_t)i0 * rsl + x;
        const float* hp  = hi + (size_t)r * ssh + (size_t)i0 * rsh + x;
        float acc = 0.f;
        #pragma unroll
        for (int tt = 0; tt < 6; ++tt)
            acc += lop[(size_t)tt * rsl] * cl[tt] + hp[(size_t)tt * rsh] * ch[tt];
        out[((size_t)r * OY + u) * NX + x] = acc;
    }
}

// ---------------- synthesis along x (tight layouts), branch-free parity form -------
__global__ void idwt_x_kernel(const float* __restrict__ lo, const float* __restrict__ hi,
                              float* __restrict__ out, int R, int NY, int n)
{
    int OX = 2 * n - 10;
    GSL((long)R * NY * OX) {
        int u = (int)(idx % OX);
        long t = idx / OX;
        int y = (int)(t % NY);
        int r = (int)(t / NY);
        int par = u & 1;
        int i0  = u >> 1;
        float cl[6], ch[6];
        #pragma unroll
        for (int tt = 0; tt < 6; ++tt) {
            cl[tt] = F_LO[2 * tt + 1 - par];
            ch[tt] = F_HI[2 * tt + 1 - par];
        }
        const float* lop = lo + ((size_t)r * NY + y) * n + i0;
        const float* hp  = hi + ((size_t)r * NY + y) * n + i0;
        float acc = 0.f;
        #pragma unroll
        for (int tt = 0; tt < 6; ++tt)
            acc += lop[tt] * cl[tt] + hp[tt] * ch[tt];
        out[((size_t)r * NY + y) * OX + u] = acc;
    }
}

// ---------------- all four coarsest mixes in ONE launch ----------------------------
// q=0: (L3, w+0)   -> L3m ; q=1..3: (Y2+(q-1)D3, w+q*WKS) -> Y2m+(q-1)D3
__global__ void mix4_kernel(const float* __restrict__ L3, const float* __restrict__ Y2,
                            const float* __restrict__ wc_l, float* __restrict__ L3m,
                            float* __restrict__ Y2m, long D3, int NB)
{
    const long PER = 48L * 1681;
    const size_t WKS = 48 * 48 * (size_t)1681;
    GSL(4 * PER) {
        int q = (int)(idx / PER);
        long r = idx % PER;
        const float* in = (q == 0) ? L3 : Y2 + (size_t)(q - 1) * D3;
        const float* wk = wc_l + (size_t)q * WKS;
        float* out      = (q == 0) ? L3m : Y2m + (size_t)(q - 1) * D3;
        int p = (int)(r % 1681);
        int o = (int)(r / 1681);
        float acc[8] = {0.f,0.f,0.f,0.f,0.f,0.f,0.f,0.f};
        for (int i = 0; i < 48; ++i) {
            float w = wk[(size_t)(i * 48 + o) * 1681 + p];
            for (int b = 0; b < NB; ++b)
                acc[b] += in[(size_t)(b * 48 + i) * 1681 + p] * w;
        }
        for (int b = 0; b < NB; ++b)
            out[(size_t)(b * 48 + o) * 1681 + p] = acc[b];
    }
}

// ---------------- fused: IDWT-L1 row synthesis + h = act(h1 + cw@h + cb), in place -
// Grid = NB*256*4 blocks. Block = (local batch b, row y, x-tile of 64 px). The block
// stages all 48 channels of its 64 pixels into LDS (coalesced), then 256 threads
// compute 48ch x 64px items (12 per thread). Pixel ownership is exclusive per block,
// so the in-place update of h stays race-free. The h1 tap loop is the branch-free
// parity form (parity fixed per thread -> coefficients hoisted out of the item loop).
__global__ __launch_bounds__(256) void idwt_x_combine_kernel(
        const float* __restrict__ w1a, const float* __restrict__ w1b,
        float* __restrict__ h, const float* __restrict__ cw,
        const float* __restrict__ cb, int do_gelu)
{
    __shared__ float s_h[48 * 64];
    __shared__ float s_w[2304];
    __shared__ float s_b[48];
    int tid = threadIdx.x;
    int bi = blockIdx.x;
    int xt = bi & 3;
    int y  = (bi >> 2) & 255;
    int b  = bi >> 10;
    int x0 = xt << 6;
    for (int j = tid; j < 2304; j += 256) s_w[j] = cw[j];
    if (tid < 48) s_b[tid] = cb[tid];
    for (int j = tid; j < 48 * 64; j += 256) {
        int i = j >> 6, xx = j & 63;
        s_h[j] = h[((size_t)(b * 48 + i) * 256 + y) * 256 + x0 + xx];
    }
    __syncthreads();
    // parity-fixed synthesis coefficients for this thread's x
    int xpx  = x0 + (tid & 63);
    int par  = xpx & 1;
    int i0   = xpx >> 1;               // i0+5 <= 132 < 133, no bounds check needed
    float cl[6], ch[6];
    #pragma unroll
    for (int tt = 0; tt < 6; ++tt) {
        cl[tt] = F_LO[2 * tt + 1 - par];
        ch[tt] = F_HI[2 * tt + 1 - par];
    }
    #pragma unroll
    for (int k = 0; k < 12; ++k) {
        int m = (k << 8) + tid;          // per wave: same c, xx = lane (conflict-free)
        int c  = m >> 6;
        int xx = m & 63;
        int x  = x0 + xx;
        const float* lop = w1a + ((size_t)(b * 48 + c) * 256 + y) * 133 + i0;
        const float* hp  = w1b + ((size_t)(b * 48 + c) * 256 + y) * 133 + i0;
        float h1 = 0.f;
        #pragma unroll
        for (int tt = 0; tt < 6; ++tt)
            h1 += lop[tt] * cl[tt] + hp[tt] * ch[tt];
        float h2 = s_b[c];
        const float* wr = s_w + c * 48;
        const float* vr = s_h + xx;
        #pragma unroll
        for (int i = 0; i < 48; ++i) h2 += wr[i] * vr[i << 6];
        float r = h1 + h2;
        h[((size_t)(b * 48 + c) * 256 + y) * 256 + x] = do_gelu ? gelu_f(r) : r;
    }
}

// ---------------- head: crop 255x255, gelu(h@fc1+b1)@fc2+b2 ------------------------
__global__ __launch_bounds__(256) void head_kernel(const float* __restrict__ h,
        const float* __restrict__ w1, const float* __restrict__ b1,
        const float* __restrict__ w2, const float* __restrict__ b2,
        float* __restrict__ out)
{
    __shared__ float s_w1[3072];
    __shared__ float s_b1[64];
    __shared__ float s_w2[64];
    int tid = threadIdx.x;
    for (int j = tid; j < 3072; j += 256) s_w1[j] = w1[j];
    if (tid < 64) { s_b1[tid] = b1[tid]; s_w2[tid] = w2[tid]; }
    __syncthreads();
    int b = blockIdx.x / 255;
    int y = blockIdx.x % 255;
    if (tid >= 255) return;
    float v[48];
    #pragma unroll
    for (int c = 0; c < 48; ++c)
        v[c] = h[((size_t)(b * 48 + c) * 256 + y) * 256 + tid];
    float acc = b2[0];
    for (int hh = 0; hh < 64; ++hh) {
        float s = s_b1[hh];
        #pragma unroll
        for (int i = 0; i < 48; ++i) s += v[i] * s_w1[i * 64 + hh];
        acc += gelu_f(s) * s_w2[hh];
    }
    out[(size_t)(b * 255 + y) * 255 + tid] = acc;
}

extern "C" void kernel_launch(void* const* d_in, const int* in_sizes, int n_in,
                              void* d_out, int out_size, void* d_ws, size_t ws_size,
                              hipStream_t stream)
{
    const float* x    = (const float*)d_in[0];
    const float* fc0w = (const float*)d_in[1];
    const float* fc0b = (const float*)d_in[2];
    const float* wc[4] = { (const float*)d_in[3], (const float*)d_in[4],
                           (const float*)d_in[5], (const float*)d_in[6] };
    const float* cw   = (const float*)d_in[7];
    const float* cb   = (const float*)d_in[8];
    const float* fc1w = (const float*)d_in[9];
    const float* fc1b = (const float*)d_in[10];
    const float* fc2w = (const float*)d_in[11];
    const float* fc2b = (const float*)d_in[12];
    float* out = (float*)d_out;
    (void)in_sizes; (void)n_in;

    // ---- batch-chunked workspace plan (adaptive; cb_n=1 needs 127.4 MB) ----------
    const size_t A_F     = 25165824;  // (8,48,256,256)
    const size_t PER_SHT = 139119;    // 68096 (W1/mid) + 53067 (Y0) + 17956 (L1)
    int cb_n = 0;
    for (int c = 8; c >= 1; c >>= 1) {
        if ((A_F + (size_t)c * 48 * PER_SHT) * 4ull <= ws_size) { cb_n = c; break; }
    }
    if (cb_n == 0) {
        fill_kernel<<<dim3(2033), 256, 0, stream>>>(out, (long)out_size,
                                                    (float)(ws_size >> 20));
        return;
    }
    const int S = cb_n * 48;
    float* ws = (float*)d_ws;
    float* A    = ws;
    float* CH   = A + A_F;
    float* W1a  = CH;                           // (S,256,133)
    float* W1b  = CH + (size_t)S * 34048;
    float* Y0   = CH + (size_t)S * 68096;       // 3 x (S,133,133)
    float* L1c  = Y0 + (size_t)S * 53067;       // (S,134,134)
    float* W2a  = CH;                           // mid-phase aliases W1 region
    float* W2b  = W2a + (size_t)S * 9648;
    float* Y1   = W2b + (size_t)S * 9648;
    float* L2   = Y1  + (size_t)S * 3 * 5184;
    float* W3a  = L2  + (size_t)S * 5184;
    float* W3b  = W3a + (size_t)S * 2952;
    float* Y2   = W3b + (size_t)S * 2952;
    float* Y2m  = Y2  + (size_t)S * 3 * 1681;
    float* L3   = Y2m + (size_t)S * 3 * 1681;
    float* L3m  = L3  + (size_t)S * 1681;

    const size_t D1 = (size_t)S * 17689, D2 = (size_t)S * 5184, D3 = (size_t)S * 1681;
    auto g = [](long n) { return dim3((unsigned)((n + 255) / 256)); };

    fc0_kernel<<<g(25165824L), 256, 0, stream>>>(x, fc0w, fc0b, A);

    for (int layer = 0; layer < 4; ++layer) {
        const float* w = wc[layer];
        for (int b0 = 0; b0 < 8; b0 += cb_n) {
            float* Ac = A + (size_t)b0 * 48 * 65536;
            // ---- DWT level 1: 256 -> 133
            dwt_x_kernel<<<g((long)S*256*133), 256, 0, stream>>>(Ac, W1a, W1b, S, 256, 256, 133);
            dwt_y_pair_kernel<<<g(2L*S*133*133), 256, 0, stream>>>(
                    W1a, L1c, Y0 + 0*D1, W1b, Y0 + 1*D1, Y0 + 2*D1, S, 256, 133, 133);
            // ---- DWT level 2: 133 -> 72
            dwt_x_kernel<<<g((long)S*133*72), 256, 0, stream>>>(L1c, W2a, W2b, S, 133, 133, 72);
            dwt_y_pair_kernel<<<g(2L*S*72*72), 256, 0, stream>>>(
                    W2a, L2, Y1 + 0*D2, W2b, Y1 + 1*D2, Y1 + 2*D2, S, 133, 72, 72);
            // ---- DWT level 3: 72 -> 41
            dwt_x_kernel<<<g((long)S*72*41), 256, 0, stream>>>(L2, W3a, W3b, S, 72, 72, 41);
            dwt_y_pair_kernel<<<g(2L*S*41*41), 256, 0, stream>>>(
                    W3a, L3, Y2 + 0*D3, W3b, Y2 + 1*D3, Y2 + 2*D3, S, 72, 41, 41);
            // ---- coarsest-level channel mixes, one launch
            mix4_kernel<<<g(4L*48*1681), 256, 0, stream>>>(L3, Y2, w, L3m, Y2m, (long)D3, cb_n);
            // ---- IDWT level 3: 41 -> 72
            idwt_y_pair_kernel<<<g(2L*S*72*41), 256, 0, stream>>>(
                    L3m, Y2m + 0*D3, W3a, 41, 1681, 41, 1681,
                    Y2m + 1*D3, Y2m + 2*D3, W3b, 41, 1681, 41, 1681, S, 41, 41);
            idwt_x_kernel<<<g((long)S*72*72), 256, 0, stream>>>(W3a, W3b, L2, S, 72, 41);
            // ---- IDWT level 2: 72 -> 134
            idwt_y_pair_kernel<<<g(2L*S*134*72), 256, 0, stream>>>(
                    L2, Y1 + 0*D2, W2a, 72, 5184, 72, 5184,
                    Y1 + 1*D2, Y1 + 2*D2, W2b, 72, 5184, 72, 5184, S, 72, 72);
            idwt_x_kernel<<<g((long)S*134*134), 256, 0, stream>>>(W2a, W2b, L1c, S, 134, 72);
            // ---- IDWT level 1: ll (S,134,134) cropped to 133x133 via strides
            idwt_y_pair_kernel<<<g(2L*S*256*133), 256, 0, stream>>>(
                    L1c, Y0 + 0*D1, W1a, 134, 17956, 133, 17689,
                    Y0 + 1*D1, Y0 + 2*D1, W1b, 133, 17689, 133, 17689, S, 133, 133);
            // ---- fused IDWT-L1 row synthesis + combine + activation, in place on Ac
            idwt_x_combine_kernel<<<cb_n * 1024, 256, 0, stream>>>(W1a, W1b, Ac,
                    cw + layer * 2304, cb + layer * 48, layer < 3 ? 1 : 0);
        }
    }

    head_kernel<<<8 * 255, 256, 0, stream>>>(A, fc1w, fc1b, fc2w, fc2b, out);
}